// Round 4
// baseline (392.350 us; speedup 1.0000x reference)
//
#include <hip/hip_runtime.h>
#include <hip/hip_bf16.h>

#define B_ 2
#define S_ 2048
#define D_ 1024
#define H_ 16
#define FF_ 4096
#define M_ (B_*S_)   // 4096

using u16 = unsigned short;
using u32 = unsigned int;
typedef __attribute__((ext_vector_type(8))) short short8;
typedef __attribute__((ext_vector_type(4))) float f32x4;
typedef __attribute__((ext_vector_type(16))) float f32x16;
typedef __attribute__((ext_vector_type(4))) unsigned short u16x4;
typedef __attribute__((ext_vector_type(4))) unsigned int u32x4;

static __device__ __forceinline__ u16 f2bf(float f) {
  __hip_bfloat16 h = __float2bfloat16(f);
  return *reinterpret_cast<u16*>(&h);
}
static __device__ __forceinline__ float bf2f(u16 u) {
  __hip_bfloat16 h; *reinterpret_cast<u16*>(&h) = u;
  return __bfloat162float(h);
}

#define GLDS(gp, lp) __builtin_amdgcn_global_load_lds( \
    (const __attribute__((address_space(1))) void*)(gp), \
    (__attribute__((address_space(3))) void*)(lp), 16, 0, 0)

#define MFMA16(a, b, c) __builtin_amdgcn_mfma_f32_16x16x32_bf16(a, b, c, 0, 0, 0)
#define BAR() __builtin_amdgcn_s_barrier()
#define LGKM0() asm volatile("s_waitcnt lgkmcnt(0)" ::: "memory")
#define VMC(n) asm volatile("s_waitcnt vmcnt(" #n ")" ::: "memory")

// ---------------- fp32 -> bf16 conversion ----------------
__global__ __launch_bounds__(256) void conv_f32_bf16(
    const float* __restrict__ src, u16* __restrict__ dst, int n4) {
  int i = blockIdx.x * 256 + threadIdx.x;
  if (i < n4) {
    float4 v = reinterpret_cast<const float4*>(src)[i];
    u16x4 o;
    o.x = f2bf(v.x); o.y = f2bf(v.y); o.z = f2bf(v.z); o.w = f2bf(v.w);
    reinterpret_cast<u16x4*>(dst)[i] = o;
  }
}

// ---------------- LayerNorm (non-parametric), fp32 in -> bf16 out ----------------
__global__ __launch_bounds__(256) void ln_rows(
    const float* __restrict__ x, u16* __restrict__ out) {
  int row = blockIdx.x;
  int t = threadIdx.x;
  float4 v = reinterpret_cast<const float4*>(x + (size_t)row * D_)[t];
  float s  = v.x + v.y + v.z + v.w;
  float ss = v.x*v.x + v.y*v.y + v.z*v.z + v.w*v.w;
  #pragma unroll
  for (int off = 1; off < 64; off <<= 1) {
    s  += __shfl_xor(s,  off, 64);
    ss += __shfl_xor(ss, off, 64);
  }
  __shared__ float rs[4], rss[4];
  int wid = t >> 6;
  if ((t & 63) == 0) { rs[wid] = s; rss[wid] = ss; }
  __syncthreads();
  s  = rs[0] + rs[1] + rs[2] + rs[3];
  ss = rss[0] + rss[1] + rss[2] + rss[3];
  float mean = s * (1.0f / D_);
  float var  = ss * (1.0f / D_) - mean * mean;
  float r = rsqrtf(var + 1e-5f);
  u16x4 o;
  o.x = f2bf((v.x - mean) * r);
  o.y = f2bf((v.y - mean) * r);
  o.z = f2bf((v.z - mean) * r);
  o.w = f2bf((v.w - mean) * r);
  reinterpret_cast<u16x4*>(out + (size_t)row * D_)[t] = o;
}

// ---------------- 128x128 BT GEMM (N=1024 shapes) ----------------
template<int MODE>
__global__ __launch_bounds__(256) void gemm_bt(
    const u16* __restrict__ A, const u16* __restrict__ W,
    void* __restrict__ C, const u16* __restrict__ aux,
    const float* __restrict__ res, int M, int N, int K)
{
  __shared__ u16 As[128 * 64];
  __shared__ u16 Bs[128 * 64];
  const int tid = threadIdx.x;
  const int wid = tid >> 6, lane = tid & 63;
  const int g = lane >> 4, c = lane & 15;
  const int bm = blockIdx.y, bn = blockIdx.x;
  const int wm = wid >> 1, wn = wid & 1;

  f32x4 acc[4][4];
  #pragma unroll
  for (int i = 0; i < 4; i++)
    #pragma unroll
    for (int j = 0; j < 4; j++) acc[i][j] = {0.f, 0.f, 0.f, 0.f};

  for (int k0 = 0; k0 < K; k0 += 64) {
    #pragma unroll
    for (int i = 0; i < 4; i++) {
      int loff = (wid * 4 + i) * 1024 + lane * 16;
      int row  = loff >> 7;
      int colb = loff & 127;
      const char* ga = (const char*)A + ((size_t)(bm * 128 + row) * K + k0) * 2 + colb;
      GLDS(ga, (char*)As + loff);
      const char* gb = (const char*)W + ((size_t)(bn * 128 + row) * K + k0) * 2 + colb;
      GLDS(gb, (char*)Bs + loff);
    }
    __syncthreads();

    short8 af[2][4], bfr[2][4];
    #pragma unroll
    for (int ks = 0; ks < 2; ks++)
      #pragma unroll
      for (int m = 0; m < 4; m++)
        af[ks][m] = *reinterpret_cast<const short8*>(
            &As[(wm * 64 + m * 16 + c) * 64 + ks * 32 + g * 8]);
    #pragma unroll
    for (int ks = 0; ks < 2; ks++)
      #pragma unroll
      for (int n = 0; n < 4; n++)
        bfr[ks][n] = *reinterpret_cast<const short8*>(
            &Bs[(wn * 64 + n * 16 + c) * 64 + ks * 32 + g * 8]);
    #pragma unroll
    for (int m = 0; m < 4; m++)
      #pragma unroll
      for (int n = 0; n < 4; n++) {
        acc[m][n] = MFMA16(af[0][m], bfr[0][n], acc[m][n]);
        acc[m][n] = MFMA16(af[1][m], bfr[1][n], acc[m][n]);
      }
    __syncthreads();
  }

  #pragma unroll
  for (int m = 0; m < 4; m++)
    #pragma unroll
    for (int n = 0; n < 4; n++)
      #pragma unroll
      for (int r = 0; r < 4; r++) {
        int gr = bm * 128 + wm * 64 + m * 16 + g * 4 + r;
        int gc = bn * 128 + wn * 64 + n * 16 + c;
        size_t idx = (size_t)gr * N + gc;
        float v = acc[m][n][r];
        if (MODE == 0) {
          ((u16*)C)[idx] = f2bf(v);
        } else if (MODE == 1) {
          ((float*)C)[idx] = v + res[idx];
        } else if (MODE == 2) {
          ((u16*)C)[idx] = f2bf(v / (1.0f + __expf(-v)));
        } else {
          ((u16*)C)[idx] = f2bf(v * bf2f(aux[idx]));
        }
      }
}

// ---------------- 256x256 8-phase BT GEMM (T2+T3+T4+T5) ----------------
template<int MODE>
__global__ __launch_bounds__(512, 2) void gemm256(
    const u16* __restrict__ A, const u16* __restrict__ W,
    void* __restrict__ C, const u16* __restrict__ aux, int M, int N, int K)
{
  __shared__ u16 lds[65536];
  const int tid = threadIdx.x;
  const int wid = tid >> 6, lane = tid & 63;
  const int g = lane >> 4, c = lane & 15;
  const int wm = wid >> 2, wn = wid & 3;

  const int gridN = N >> 8;
  int nwg = gridDim.x * gridDim.y;
  int lin = blockIdx.y * gridDim.x + blockIdx.x;
  lin = (lin & 7) * (nwg >> 3) + (lin >> 3);
  const int bm = lin / gridN, bn = lin % gridN;
  const int NT = K >> 6;

  f32x4 acc[8][4];
  #pragma unroll
  for (int i = 0; i < 8; i++)
    #pragma unroll
    for (int j = 0; j < 4; j++) acc[i][j] = {0.f, 0.f, 0.f, 0.f};

  auto stage = [&](int sel, int t, int half) {
    const u16* src = sel ? W : A;
    const int tilerow = (sel ? bn : bm) * 256 + half * 128;
    const int ldsb = sel * 32768 + (t & 1) * 16384 + half * 8192;
    #pragma unroll
    for (int i = 0; i < 2; i++) {
      int j = i * 512 + tid;
      int row = j >> 3, col16 = j & 7;
      const u16* gp = src + (size_t)(tilerow + row) * K + t * 64 + ((col16 ^ (row & 7)) << 3);
      GLDS(gp, (char*)lds + ldsb * 2 + j * 16);
    }
  };
  auto ldA = [&](short8 (&a)[2][4], int buf, int mh) {
    #pragma unroll
    for (int ks = 0; ks < 2; ks++)
      #pragma unroll
      for (int m = 0; m < 4; m++) {
        int rh = wm * 16 + m * 32 + c;
        a[ks][m] = *reinterpret_cast<const short8*>(
            &lds[buf * 16384 + mh * 8192 + rh * 64 + ((((ks << 2) | g) ^ (rh & 7)) << 3)]);
      }
  };
  auto ldB = [&](short8 (&b)[2][2], int buf, int nh) {
    #pragma unroll
    for (int ks = 0; ks < 2; ks++)
      #pragma unroll
      for (int n = 0; n < 2; n++) {
        int rh = wn * 16 + n * 64 + c;
        b[ks][n] = *reinterpret_cast<const short8*>(
            &lds[32768 + buf * 16384 + nh * 8192 + rh * 64 + ((((ks << 2) | g) ^ (rh & 7)) << 3)]);
      }
  };

#define MFMA_Q(a, b, mb, nb)                                            \
  __builtin_amdgcn_s_setprio(1);                                        \
  _Pragma("unroll")                                                     \
  for (int m = 0; m < 4; m++)                                           \
    _Pragma("unroll")                                                   \
    for (int n = 0; n < 2; n++) {                                       \
      acc[(mb)+m][(nb)+n] = MFMA16(a[0][m], b[0][n], acc[(mb)+m][(nb)+n]); \
      acc[(mb)+m][(nb)+n] = MFMA16(a[1][m], b[1][n], acc[(mb)+m][(nb)+n]); \
    }                                                                   \
  __builtin_amdgcn_s_setprio(0);

  stage(0, 0, 0); stage(1, 0, 0); stage(0, 0, 1); stage(1, 0, 1);
  stage(0, 1, 0); stage(1, 1, 0);
  VMC(4);
  BAR();

  for (int t = 0; t < NT; t += 2) {
    const int buf = t & 1;
    short8 a0[2][4], a1[2][4], b0[2][2], b1[2][2];
    ldA(a0, buf, 0); ldB(b0, buf, 0);
    stage(0, t + 1, 1);
    BAR(); LGKM0();
    MFMA_Q(a0, b0, 0, 0);
    BAR();
    ldB(b1, buf, 1);
    stage(1, t + 1, 1);
    BAR(); LGKM0();
    MFMA_Q(a0, b1, 0, 2);
    BAR();
    ldA(a1, buf, 1);
    if (t + 2 < NT) stage(0, t + 2, 0);
    BAR(); LGKM0();
    MFMA_Q(a1, b0, 4, 0);
    BAR();
    if (t + 2 < NT) { stage(1, t + 2, 0); VMC(4); } else { VMC(0); }
    BAR(); LGKM0();
    MFMA_Q(a1, b1, 4, 2);
    BAR();
    ldA(a0, buf ^ 1, 0); ldB(b0, buf ^ 1, 0);
    if (t + 2 < NT) stage(0, t + 2, 1);
    BAR(); LGKM0();
    MFMA_Q(a0, b0, 0, 0);
    BAR();
    ldB(b1, buf ^ 1, 1);
    if (t + 2 < NT) stage(1, t + 2, 1);
    BAR(); LGKM0();
    MFMA_Q(a0, b1, 0, 2);
    BAR();
    ldA(a1, buf ^ 1, 1);
    if (t + 3 < NT) stage(0, t + 3, 0);
    BAR(); LGKM0();
    MFMA_Q(a1, b0, 4, 0);
    BAR();
    if (t + 3 < NT) { stage(1, t + 3, 0); VMC(4); } else { VMC(0); }
    BAR(); LGKM0();
    MFMA_Q(a1, b1, 4, 2);
    BAR();
  }

  #pragma unroll
  for (int m = 0; m < 8; m++)
    #pragma unroll
    for (int n = 0; n < 4; n++)
      #pragma unroll
      for (int r = 0; r < 4; r++) {
        int gr = bm * 256 + (m >> 2) * 128 + wm * 16 + (m & 3) * 32 + g * 4 + r;
        int gc = bn * 256 + (n >> 1) * 128 + wn * 16 + (n & 1) * 64 + c;
        size_t idx = (size_t)gr * N + gc;
        float v = acc[m][n][r];
        if (MODE == 0) {
          ((u16*)C)[idx] = f2bf(v);
        } else if (MODE == 2) {
          ((u16*)C)[idx] = f2bf(v / (1.0f + __expf(-v)));
        } else {
          ((u16*)C)[idx] = f2bf(v * bf2f(aux[idx]));
        }
      }
#undef MFMA_Q
}

// ---------------- V transpose: qkv v-section -> vT [B*H, 64, S] ----------------
__global__ __launch_bounds__(256) void transpose_v(
    const u16* __restrict__ qkv, u16* __restrict__ vT) {
  __shared__ u16 t[64][66];
  int bh = blockIdx.y;
  int s0 = blockIdx.x * 64;
  int b = bh >> 4, h = bh & 15;
  int tid = threadIdx.x;
  #pragma unroll
  for (int it = 0; it < 2; it++) {
    int idx = it * 256 + tid;
    int row = idx >> 3;
    int cc  = (idx & 7) * 8;
    const u16* src = qkv + ((size_t)(b * S_ + s0 + row)) * 3072 + 2048 + h * 64 + cc;
    short8 v = *reinterpret_cast<const short8*>(src);
    #pragma unroll
    for (int j = 0; j < 8; j++) t[row][cc + j] = (u16)v[j];
  }
  __syncthreads();
  #pragma unroll
  for (int it = 0; it < 2; it++) {
    int idx = it * 256 + tid;
    int d  = idx >> 3;
    int sc = (idx & 7) * 8;
    short8 o;
    #pragma unroll
    for (int j = 0; j < 8; j++) o[j] = (short)t[sc + j][d];
    *reinterpret_cast<short8*>(vT + ((size_t)bh * 64 + d) * S_ + s0 + sc) = o;
  }
}

// ---------------- split-KV causal flash attention ----------------
// unit = (bh, qt, ci): kv-chunk of <=16 kv-tiles (32 wide each).
// 160 units per bh, 5120 total, 1 wave each. Partials: O bf16 [32q][64d],
// m/l per q-row. Combine kernel merges <=4 chunks per (bh,qt).
__global__ __launch_bounds__(256) void attn_split(
    const u16* __restrict__ qkv, const u16* __restrict__ vT,
    u16* __restrict__ pO, float* __restrict__ pML) {
  const int lane = threadIdx.x & 63;
  const int wid  = threadIdx.x >> 6;
  const int l31  = lane & 31;
  const int half = lane >> 5;

  int lin = blockIdx.x;                       // 0..1279
  int swz = (lin & 7) * 160 + (lin >> 3);     // XCD swizzle (1280%8==0)
  int bh  = swz / 40;                         // 4 heads per XCD chunk
  int u   = 159 - ((swz % 40) * 4 + wid);     // canonical unit, heavy first
  int qt, ci;
  if (u < 16)      { qt = u;                  ci = 0; }
  else if (u < 48) { qt = 16 + ((u - 16) >> 1); ci = (u - 16) & 1; }
  else if (u < 96) { qt = 32 + (u - 48) / 3;  ci = (u - 48) % 3; }
  else             { qt = 48 + ((u - 96) >> 2); ci = (u - 96) & 3; }
  const int kt0 = ci * 16;
  const int kt1 = min(qt, kt0 + 15);          // inclusive
  const int punit = bh * 160 + u;

  const int b = bh >> 4, hd = bh & 15;
  const int q_base = qt * 32;

  const u16* Qb = qkv + ((size_t)(b * S_ + q_base + l31)) * 3072 + hd * 64;
  const u16* Kb = qkv + (size_t)b * S_ * 3072 + 1024 + hd * 64;
  const u16* Vt = vT + (size_t)bh * 64 * S_;

  short8 qf[4];
  #pragma unroll
  for (int dt = 0; dt < 4; dt++) {
    short8 v = *reinterpret_cast<const short8*>(Qb + dt * 16 + half * 8);
    #pragma unroll
    for (int j = 0; j < 8; j++) v[j] = (short)f2bf(bf2f((u16)v[j]) * 0.125f);
    qf[dt] = v;
  }

  f32x16 o0, o1;
  #pragma unroll
  for (int r = 0; r < 16; r++) { o0[r] = 0.f; o1[r] = 0.f; }
  float m = -1e30f, lsum = 0.f;

  auto loadK = [&](int kt, short8 (&kf)[4]) {
    #pragma unroll
    for (int dt = 0; dt < 4; dt++)
      kf[dt] = *reinterpret_cast<const short8*>(
          Kb + (size_t)(kt * 32 + l31) * 3072 + dt * 16 + half * 8);
  };
  auto loadV = [&](int kt, short8 (&vf)[4]) {
    vf[0] = *reinterpret_cast<const short8*>(Vt + (size_t)l31        * S_ + kt * 32 + half * 8);
    vf[1] = *reinterpret_cast<const short8*>(Vt + (size_t)l31        * S_ + kt * 32 + 16 + half * 8);
    vf[2] = *reinterpret_cast<const short8*>(Vt + (size_t)(32 + l31) * S_ + kt * 32 + half * 8);
    vf[3] = *reinterpret_cast<const short8*>(Vt + (size_t)(32 + l31) * S_ + kt * 32 + 16 + half * 8);
  };

  short8 kf[4], vf[4];
  loadK(kt0, kf); loadV(kt0, vf);

  for (int kt = kt0; ; kt++) {
    const bool lastit = (kt == kt1);
    const bool diag   = (kt == qt);
    short8 kn[4], vn[4];
    if (!lastit) { loadK(kt + 1, kn); loadV(kt + 1, vn); }

    f32x16 s;
    #pragma unroll
    for (int r = 0; r < 16; r++) s[r] = 0.f;
    __builtin_amdgcn_s_setprio(1);
    #pragma unroll
    for (int dt = 0; dt < 4; dt++)
      s = __builtin_amdgcn_mfma_f32_32x32x16_bf16(kf[dt], qf[dt], s, 0, 0, 0);
    __builtin_amdgcn_s_setprio(0);

    float p[16];
    #pragma unroll
    for (int r = 0; r < 16; r++) {
      p[r] = s[r];
      if (diag) {
        int kloc = half * 4 + (r & 3) + 8 * (r >> 2);
        if (kloc > l31) p[r] = -1e30f;
      }
    }
    float rm = p[0];
    #pragma unroll
    for (int r = 1; r < 16; r++) rm = fmaxf(rm, p[r]);
    rm = fmaxf(rm, __shfl_xor(rm, 32, 64));

    if (__any(rm > m + 8.0f)) {               // defer-max rescale (T13)
      float mn = fmaxf(m, rm);
      float alpha = __expf(m - mn);
      m = mn;
      lsum *= alpha;
      #pragma unroll
      for (int r = 0; r < 16; r++) {
        int row = (r & 3) + 8 * (r >> 2) + 4 * half;
        float ar = __shfl(alpha, row, 64);
        o0[r] *= ar; o1[r] *= ar;
      }
    }
    float rs = 0.f;
    #pragma unroll
    for (int r = 0; r < 16; r++) { p[r] = __expf(p[r] - m); rs += p[r]; }
    rs += __shfl_xor(rs, 32, 64);
    lsum += rs;

    u32 pk[8], sp[8];
    #pragma unroll
    for (int i = 0; i < 8; i++) {
      pk[i] = (u32)f2bf(p[2 * i]) | ((u32)f2bf(p[2 * i + 1]) << 16);
      sp[i] = (u32)__shfl_xor((int)pk[i], 32, 64);
    }
    u32x4 a0 = { half ? sp[2] : pk[0], half ? sp[3] : pk[1],
                 half ? pk[2] : sp[0], half ? pk[3] : sp[1] };
    u32x4 a1 = { half ? sp[6] : pk[4], half ? sp[7] : pk[5],
                 half ? pk[6] : sp[4], half ? pk[7] : sp[5] };
    short8 pa0 = *reinterpret_cast<short8*>(&a0);
    short8 pa1 = *reinterpret_cast<short8*>(&a1);

    __builtin_amdgcn_s_setprio(1);
    o0 = __builtin_amdgcn_mfma_f32_32x32x16_bf16(pa0, vf[0], o0, 0, 0, 0);
    o0 = __builtin_amdgcn_mfma_f32_32x32x16_bf16(pa1, vf[1], o0, 0, 0, 0);
    o1 = __builtin_amdgcn_mfma_f32_32x32x16_bf16(pa0, vf[2], o1, 0, 0, 0);
    o1 = __builtin_amdgcn_mfma_f32_32x32x16_bf16(pa1, vf[3], o1, 0, 0, 0);
    __builtin_amdgcn_s_setprio(0);

    if (lastit) break;
    #pragma unroll
    for (int i = 0; i < 4; i++) { kf[i] = kn[i]; vf[i] = vn[i]; }
  }

  // write partials (bf16 O, f32 m/l)
  #pragma unroll
  for (int r = 0; r < 16; r++) {
    int row = (r & 3) + 8 * (r >> 2) + 4 * half;
    pO[(size_t)punit * 2048 + row * 64 + l31]      = f2bf(o0[r]);
    pO[(size_t)punit * 2048 + row * 64 + 32 + l31] = f2bf(o1[r]);
  }
  if (half == 0) {
    pML[punit * 64 + l31]      = m;
    pML[punit * 64 + 32 + l31] = lsum;
  }
}

// ---------------- combine partials -> att ----------------
__global__ __launch_bounds__(256) void attn_combine(
    const u16* __restrict__ pO, const float* __restrict__ pML,
    u16* __restrict__ att) {
  const int lane = threadIdx.x & 63;   // d-column
  const int wid  = threadIdx.x >> 6;
  int gw = blockIdx.x * 4 + wid;       // 0..2047
  int bh = gw >> 6, qt = gw & 63;
  int b = bh >> 4, hd = bh & 15;
  int nc = (qt >> 4) + 1;
  int base;
  if (qt < 16)      base = qt;
  else if (qt < 32) base = 16 + (qt - 16) * 2;
  else if (qt < 48) base = 48 + (qt - 32) * 3;
  else              base = 96 + (qt - 48) * 4;
  int p0 = bh * 160 + base;

  for (int q = 0; q < 32; q++) {
    float m0 = pML[p0 * 64 + q];
    float l0 = pML[p0 * 64 + 32 + q];
    float m1 = nc > 1 ? pML[(p0 + 1) * 64 + q]      : -1e30f;
    float l1 = nc > 1 ? pML[(p0 + 1) * 64 + 32 + q] : 0.f;
    float m2 = nc > 2 ? pML[(p0 + 2) * 64 + q]      : -1e30f;
    float l2 = nc > 2 ? pML[(p0 + 2) * 64 + 32 + q] : 0.f;
    float m3 = nc > 3 ? pML[(p0 + 3) * 64 + q]      : -1e30f;
    float l3 = nc > 3 ? pML[(p0 + 3) * 64 + 32 + q] : 0.f;
    float M = fmaxf(fmaxf(m0, m1), fmaxf(m2, m3));
    float w0 = __expf(m0 - M), w1 = __expf(m1 - M);
    float w2 = __expf(m2 - M), w3 = __expf(m3 - M);
    float L = l0 * w0 + l1 * w1 + l2 * w2 + l3 * w3;
    float o = bf2f(pO[(size_t)p0 * 2048 + q * 64 + lane]) * w0;
    if (nc > 1) o += bf2f(pO[(size_t)(p0 + 1) * 2048 + q * 64 + lane]) * w1;
    if (nc > 2) o += bf2f(pO[(size_t)(p0 + 2) * 2048 + q * 64 + lane]) * w2;
    if (nc > 3) o += bf2f(pO[(size_t)(p0 + 3) * 2048 + q * 64 + lane]) * w3;
    att[((size_t)(b * S_ + qt * 32 + q)) * D_ + hd * 64 + lane] = f2bf(o / L);
  }
}

// ---------------- host launch ----------------
extern "C" void kernel_launch(void* const* d_in, const int* in_sizes, int n_in,
                              void* d_out, int out_size, void* d_ws, size_t ws_size,
                              hipStream_t stream) {
  (void)in_sizes; (void)n_in; (void)out_size; (void)ws_size;
  const float* x    = (const float*)d_in[0];
  const float* Wq   = (const float*)d_in[1];
  const float* Wk   = (const float*)d_in[2];
  const float* Wv   = (const float*)d_in[3];
  const float* Wo   = (const float*)d_in[4];
  const float* Wff  = (const float*)d_in[5];
  const float* Wout = (const float*)d_in[6];
  float* out = (float*)d_out;

  char* ws = (char*)d_ws;
  u16*   wqkv = (u16*)(ws);                    // [3072,1024] bf16, 6MB
  u16*   wo   = (u16*)(ws + 6291456);          // [1024,1024], 2MB
  u16*   wff  = (u16*)(ws + 8388608);          // [8192,1024], 16MB
  u16*   wout = (u16*)(ws + 25165824);         // [1024,4096], 8MB
  float* x1   = (float*)(ws + 33554432);       // [4096,1024] f32, 16MB
  char*  P    = ws + 50331648;                 // reuse pool
  u16*   hbuf = (u16*)(P);                     // [4096,1024], 8MB
  u16*   qkv  = (u16*)(P + 8388608);           // [4096,3072], 24MB
  u16*   vT   = (u16*)(P + 33554432);          // [32,64,2048], 8MB
  u16*   att  = (u16*)(P + 41943040);          // [4096,1024], 8MB
  u16*   pO   = (u16*)(P + 50331648);          // [5120,2048] bf16, 21MB (attn phase only)
  float* pML  = (float*)(P + 71303168);        // [5120,64] f32, 1.3MB
  u16*   h2   = (u16*)(P);                     // reuse hbuf slot
  u16*   s1   = (u16*)(P + 8388608);           // [4096,4096], 32MB
  u16*   gbuf = (u16*)(P + 41943040);          // [4096,4096], 32MB

  conv_f32_bf16<<<1024, 256, 0, stream>>>(Wq, wqkv,               262144);
  conv_f32_bf16<<<1024, 256, 0, stream>>>(Wk, wqkv + 1048576,     262144);
  conv_f32_bf16<<<1024, 256, 0, stream>>>(Wv, wqkv + 2097152,     262144);
  conv_f32_bf16<<<1024, 256, 0, stream>>>(Wo, wo,                 262144);
  conv_f32_bf16<<<8192, 256, 0, stream>>>(Wff, wff,               2097152);
  conv_f32_bf16<<<4096, 256, 0, stream>>>(Wout, wout,             1048576);

  ln_rows<<<M_, 256, 0, stream>>>(x, hbuf);
  gemm256<0><<<dim3(12, 16), 512, 0, stream>>>(hbuf, wqkv, qkv, nullptr, M_, 3072, 1024);
  transpose_v<<<dim3(32, 32), 256, 0, stream>>>(qkv, vT);
  attn_split<<<dim3(1280), 256, 0, stream>>>(qkv, vT, pO, pML);
  attn_combine<<<dim3(512), 256, 0, stream>>>(pO, pML, att);
  gemm_bt<1><<<dim3(8, 32), 256, 0, stream>>>(att, wo, x1, nullptr, x, M_, 1024, 1024);

  ln_rows<<<M_, 256, 0, stream>>>(x1, h2);
  gemm256<2><<<dim3(16, 16), 512, 0, stream>>>(h2, wff, s1, nullptr, M_, 4096, 1024);
  gemm256<3><<<dim3(16, 16), 512, 0, stream>>>(h2, wff + 4194304, gbuf, s1, M_, 4096, 1024);
  gemm_bt<1><<<dim3(8, 32), 256, 0, stream>>>(gbuf, wout, out, nullptr, x1, M_, 1024, 4096);
}

// Round 5
// 325.634 us; speedup vs baseline: 1.2049x; 1.2049x over previous
//
#include <hip/hip_runtime.h>
#include <hip/hip_bf16.h>

#define B_ 2
#define S_ 2048
#define D_ 1024
#define H_ 16
#define FF_ 4096
#define M_ (B_*S_)   // 4096

using u16 = unsigned short;
using u32 = unsigned int;
typedef __attribute__((ext_vector_type(8))) short short8;
typedef __attribute__((ext_vector_type(4))) float f32x4;
typedef __attribute__((ext_vector_type(16))) float f32x16;
typedef __attribute__((ext_vector_type(4))) unsigned short u16x4;
typedef __attribute__((ext_vector_type(4))) unsigned int u32x4;

static __device__ __forceinline__ u16 f2bf(float f) {
  __hip_bfloat16 h = __float2bfloat16(f);
  return *reinterpret_cast<u16*>(&h);
}
static __device__ __forceinline__ float bf2f(u16 u) {
  __hip_bfloat16 h; *reinterpret_cast<u16*>(&h) = u;
  return __bfloat162float(h);
}

#define GLDS(gp, lp) __builtin_amdgcn_global_load_lds( \
    (const __attribute__((address_space(1))) void*)(gp), \
    (__attribute__((address_space(3))) void*)(lp), 16, 0, 0)

#define MFMA16(a, b, c) __builtin_amdgcn_mfma_f32_16x16x32_bf16(a, b, c, 0, 0, 0)
#define BAR() __builtin_amdgcn_s_barrier()
#define LGKM0() asm volatile("s_waitcnt lgkmcnt(0)" ::: "memory")
#define VMC(n) asm volatile("s_waitcnt vmcnt(" #n ")" ::: "memory")

// ---------------- fp32 -> bf16 conversion ----------------
__global__ __launch_bounds__(256) void conv_f32_bf16(
    const float* __restrict__ src, u16* __restrict__ dst, int n4) {
  int i = blockIdx.x * 256 + threadIdx.x;
  if (i < n4) {
    float4 v = reinterpret_cast<const float4*>(src)[i];
    u16x4 o;
    o.x = f2bf(v.x); o.y = f2bf(v.y); o.z = f2bf(v.z); o.w = f2bf(v.w);
    reinterpret_cast<u16x4*>(dst)[i] = o;
  }
}

// ---------------- LayerNorm (non-parametric), fp32 in -> bf16 out ----------------
__global__ __launch_bounds__(256) void ln_rows(
    const float* __restrict__ x, u16* __restrict__ out) {
  int row = blockIdx.x;
  int t = threadIdx.x;
  float4 v = reinterpret_cast<const float4*>(x + (size_t)row * D_)[t];
  float s  = v.x + v.y + v.z + v.w;
  float ss = v.x*v.x + v.y*v.y + v.z*v.z + v.w*v.w;
  #pragma unroll
  for (int off = 1; off < 64; off <<= 1) {
    s  += __shfl_xor(s,  off, 64);
    ss += __shfl_xor(ss, off, 64);
  }
  __shared__ float rs[4], rss[4];
  int wid = t >> 6;
  if ((t & 63) == 0) { rs[wid] = s; rss[wid] = ss; }
  __syncthreads();
  s  = rs[0] + rs[1] + rs[2] + rs[3];
  ss = rss[0] + rss[1] + rss[2] + rss[3];
  float mean = s * (1.0f / D_);
  float var  = ss * (1.0f / D_) - mean * mean;
  float r = rsqrtf(var + 1e-5f);
  u16x4 o;
  o.x = f2bf((v.x - mean) * r);
  o.y = f2bf((v.y - mean) * r);
  o.z = f2bf((v.z - mean) * r);
  o.w = f2bf((v.w - mean) * r);
  reinterpret_cast<u16x4*>(out + (size_t)row * D_)[t] = o;
}

// ---------------- 128x128 BT GEMM (N=1024 shapes) ----------------
template<int MODE>
__global__ __launch_bounds__(256) void gemm_bt(
    const u16* __restrict__ A, const u16* __restrict__ W,
    void* __restrict__ C, const u16* __restrict__ aux,
    const float* __restrict__ res, int M, int N, int K)
{
  __shared__ u16 As[128 * 64];
  __shared__ u16 Bs[128 * 64];
  const int tid = threadIdx.x;
  const int wid = tid >> 6, lane = tid & 63;
  const int g = lane >> 4, c = lane & 15;
  const int bm = blockIdx.y, bn = blockIdx.x;
  const int wm = wid >> 1, wn = wid & 1;

  f32x4 acc[4][4];
  #pragma unroll
  for (int i = 0; i < 4; i++)
    #pragma unroll
    for (int j = 0; j < 4; j++) acc[i][j] = {0.f, 0.f, 0.f, 0.f};

  for (int k0 = 0; k0 < K; k0 += 64) {
    #pragma unroll
    for (int i = 0; i < 4; i++) {
      int loff = (wid * 4 + i) * 1024 + lane * 16;
      int row  = loff >> 7;
      int colb = loff & 127;
      const char* ga = (const char*)A + ((size_t)(bm * 128 + row) * K + k0) * 2 + colb;
      GLDS(ga, (char*)As + loff);
      const char* gb = (const char*)W + ((size_t)(bn * 128 + row) * K + k0) * 2 + colb;
      GLDS(gb, (char*)Bs + loff);
    }
    __syncthreads();

    short8 af[2][4], bfr[2][4];
    #pragma unroll
    for (int ks = 0; ks < 2; ks++)
      #pragma unroll
      for (int m = 0; m < 4; m++)
        af[ks][m] = *reinterpret_cast<const short8*>(
            &As[(wm * 64 + m * 16 + c) * 64 + ks * 32 + g * 8]);
    #pragma unroll
    for (int ks = 0; ks < 2; ks++)
      #pragma unroll
      for (int n = 0; n < 4; n++)
        bfr[ks][n] = *reinterpret_cast<const short8*>(
            &Bs[(wn * 64 + n * 16 + c) * 64 + ks * 32 + g * 8]);
    #pragma unroll
    for (int m = 0; m < 4; m++)
      #pragma unroll
      for (int n = 0; n < 4; n++) {
        acc[m][n] = MFMA16(af[0][m], bfr[0][n], acc[m][n]);
        acc[m][n] = MFMA16(af[1][m], bfr[1][n], acc[m][n]);
      }
    __syncthreads();
  }

  #pragma unroll
  for (int m = 0; m < 4; m++)
    #pragma unroll
    for (int n = 0; n < 4; n++)
      #pragma unroll
      for (int r = 0; r < 4; r++) {
        int gr = bm * 128 + wm * 64 + m * 16 + g * 4 + r;
        int gc = bn * 128 + wn * 64 + n * 16 + c;
        size_t idx = (size_t)gr * N + gc;
        float v = acc[m][n][r];
        if (MODE == 0) {
          ((u16*)C)[idx] = f2bf(v);
        } else if (MODE == 1) {
          ((float*)C)[idx] = v + res[idx];
        } else if (MODE == 2) {
          ((u16*)C)[idx] = f2bf(v / (1.0f + __expf(-v)));
        } else {
          ((u16*)C)[idx] = f2bf(v * bf2f(aux[idx]));
        }
      }
}

// ---------------- 256x256 8-phase BT GEMM (T2+T3+T4+T5) ----------------
template<int MODE>
__global__ __launch_bounds__(512, 2) void gemm256(
    const u16* __restrict__ A, const u16* __restrict__ W,
    void* __restrict__ C, const u16* __restrict__ aux, int M, int N, int K)
{
  __shared__ u16 lds[65536];
  const int tid = threadIdx.x;
  const int wid = tid >> 6, lane = tid & 63;
  const int g = lane >> 4, c = lane & 15;
  const int wm = wid >> 2, wn = wid & 3;

  const int gridN = N >> 8;
  int nwg = gridDim.x * gridDim.y;
  int lin = blockIdx.y * gridDim.x + blockIdx.x;
  lin = (lin & 7) * (nwg >> 3) + (lin >> 3);
  const int bm = lin / gridN, bn = lin % gridN;
  const int NT = K >> 6;

  f32x4 acc[8][4];
  #pragma unroll
  for (int i = 0; i < 8; i++)
    #pragma unroll
    for (int j = 0; j < 4; j++) acc[i][j] = {0.f, 0.f, 0.f, 0.f};

  auto stage = [&](int sel, int t, int half) {
    const u16* src = sel ? W : A;
    const int tilerow = (sel ? bn : bm) * 256 + half * 128;
    const int ldsb = sel * 32768 + (t & 1) * 16384 + half * 8192;
    #pragma unroll
    for (int i = 0; i < 2; i++) {
      int j = i * 512 + tid;
      int row = j >> 3, col16 = j & 7;
      const u16* gp = src + (size_t)(tilerow + row) * K + t * 64 + ((col16 ^ (row & 7)) << 3);
      GLDS(gp, (char*)lds + ldsb * 2 + j * 16);
    }
  };
  auto ldA = [&](short8 (&a)[2][4], int buf, int mh) {
    #pragma unroll
    for (int ks = 0; ks < 2; ks++)
      #pragma unroll
      for (int m = 0; m < 4; m++) {
        int rh = wm * 16 + m * 32 + c;
        a[ks][m] = *reinterpret_cast<const short8*>(
            &lds[buf * 16384 + mh * 8192 + rh * 64 + ((((ks << 2) | g) ^ (rh & 7)) << 3)]);
      }
  };
  auto ldB = [&](short8 (&b)[2][2], int buf, int nh) {
    #pragma unroll
    for (int ks = 0; ks < 2; ks++)
      #pragma unroll
      for (int n = 0; n < 2; n++) {
        int rh = wn * 16 + n * 64 + c;
        b[ks][n] = *reinterpret_cast<const short8*>(
            &lds[32768 + buf * 16384 + nh * 8192 + rh * 64 + ((((ks << 2) | g) ^ (rh & 7)) << 3)]);
      }
  };

#define MFMA_Q(a, b, mb, nb)                                            \
  __builtin_amdgcn_s_setprio(1);                                        \
  _Pragma("unroll")                                                     \
  for (int m = 0; m < 4; m++)                                           \
    _Pragma("unroll")                                                   \
    for (int n = 0; n < 2; n++) {                                       \
      acc[(mb)+m][(nb)+n] = MFMA16(a[0][m], b[0][n], acc[(mb)+m][(nb)+n]); \
      acc[(mb)+m][(nb)+n] = MFMA16(a[1][m], b[1][n], acc[(mb)+m][(nb)+n]); \
    }                                                                   \
  __builtin_amdgcn_s_setprio(0);

  stage(0, 0, 0); stage(1, 0, 0); stage(0, 0, 1); stage(1, 0, 1);
  stage(0, 1, 0); stage(1, 1, 0);
  VMC(4);
  BAR();

  for (int t = 0; t < NT; t += 2) {
    const int buf = t & 1;
    short8 a0[2][4], a1[2][4], b0[2][2], b1[2][2];
    ldA(a0, buf, 0); ldB(b0, buf, 0);
    stage(0, t + 1, 1);
    BAR(); LGKM0();
    MFMA_Q(a0, b0, 0, 0);
    BAR();
    ldB(b1, buf, 1);
    stage(1, t + 1, 1);
    BAR(); LGKM0();
    MFMA_Q(a0, b1, 0, 2);
    BAR();
    ldA(a1, buf, 1);
    if (t + 2 < NT) stage(0, t + 2, 0);
    BAR(); LGKM0();
    MFMA_Q(a1, b0, 4, 0);
    BAR();
    if (t + 2 < NT) { stage(1, t + 2, 0); VMC(4); } else { VMC(0); }
    BAR(); LGKM0();
    MFMA_Q(a1, b1, 4, 2);
    BAR();
    ldA(a0, buf ^ 1, 0); ldB(b0, buf ^ 1, 0);
    if (t + 2 < NT) stage(0, t + 2, 1);
    BAR(); LGKM0();
    MFMA_Q(a0, b0, 0, 0);
    BAR();
    ldB(b1, buf ^ 1, 1);
    if (t + 2 < NT) stage(1, t + 2, 1);
    BAR(); LGKM0();
    MFMA_Q(a0, b1, 0, 2);
    BAR();
    ldA(a1, buf ^ 1, 1);
    if (t + 3 < NT) stage(0, t + 3, 0);
    BAR(); LGKM0();
    MFMA_Q(a1, b0, 4, 0);
    BAR();
    if (t + 3 < NT) { stage(1, t + 3, 0); VMC(4); } else { VMC(0); }
    BAR(); LGKM0();
    MFMA_Q(a1, b1, 4, 2);
    BAR();
  }

  #pragma unroll
  for (int m = 0; m < 8; m++)
    #pragma unroll
    for (int n = 0; n < 4; n++)
      #pragma unroll
      for (int r = 0; r < 4; r++) {
        int gr = bm * 256 + (m >> 2) * 128 + wm * 16 + (m & 3) * 32 + g * 4 + r;
        int gc = bn * 256 + (n >> 1) * 128 + wn * 16 + (n & 1) * 64 + c;
        size_t idx = (size_t)gr * N + gc;
        float v = acc[m][n][r];
        if (MODE == 0) {
          ((u16*)C)[idx] = f2bf(v);
        } else if (MODE == 2) {
          ((u16*)C)[idx] = f2bf(v / (1.0f + __expf(-v)));
        } else {
          ((u16*)C)[idx] = f2bf(v * bf2f(aux[idx]));
        }
      }
#undef MFMA_Q
}

// ---------------- V transpose: qkv v-section -> vT [B*H, 64, S] ----------------
__global__ __launch_bounds__(256) void transpose_v(
    const u16* __restrict__ qkv, u16* __restrict__ vT) {
  __shared__ u16 t[64][66];
  int bh = blockIdx.y;
  int s0 = blockIdx.x * 64;
  int b = bh >> 4, h = bh & 15;
  int tid = threadIdx.x;
  #pragma unroll
  for (int it = 0; it < 2; it++) {
    int idx = it * 256 + tid;
    int row = idx >> 3;
    int cc  = (idx & 7) * 8;
    const u16* src = qkv + ((size_t)(b * S_ + s0 + row)) * 3072 + 2048 + h * 64 + cc;
    short8 v = *reinterpret_cast<const short8*>(src);
    #pragma unroll
    for (int j = 0; j < 8; j++) t[row][cc + j] = (u16)v[j];
  }
  __syncthreads();
  #pragma unroll
  for (int it = 0; it < 2; it++) {
    int idx = it * 256 + tid;
    int d  = idx >> 3;
    int sc = (idx & 7) * 8;
    short8 o;
    #pragma unroll
    for (int j = 0; j < 8; j++) o[j] = (short)t[sc + j][d];
    *reinterpret_cast<short8*>(vT + ((size_t)bh * 64 + d) * S_ + s0 + sc) = o;
  }
}

// ---------------- split-KV causal flash attention, block-cooperative LDS K/V ----------------
// Block = (bh, q-quad qq, kv-chunk ci): 4 waves, wave w -> qt = qq*4+w.
// K tile 32x64 / V tile 64x32 staged via global_load_lds, double-buffered,
// XOR-swizzled (chunk ^ row) on source AND ds_read (rule #21).
__global__ __launch_bounds__(256) void attn_split(
    const u16* __restrict__ qkv, const u16* __restrict__ vT,
    u16* __restrict__ pO, float* __restrict__ pML) {
  __shared__ u16 Kl[2][2048];   // [buf][32 rows x 64 d]
  __shared__ u16 Vl[2][2048];   // [buf][64 rows(d) x 32 s]
  const int tid  = threadIdx.x;
  const int lane = tid & 63;
  const int wid  = tid >> 6;
  const int l31  = lane & 31;
  const int half = lane >> 5;

  int lin = blockIdx.x;                       // 0..1279
  int swz = (lin & 7) * 160 + (lin >> 3);     // XCD swizzle: 4 heads/XCD
  int bh  = swz / 40;
  int j   = swz - bh * 40;
  int qq = 15, rem = j;                       // heavy quads first
  while (rem > (qq >> 2)) { rem -= (qq >> 2) + 1; qq--; }
  int ci = rem;
  const int qt  = qq * 4 + wid;
  const int kt0 = ci * 16;
  const int nt  = min(qq * 4 + 3, kt0 + 15) - kt0;  // block-uniform iter count-1
  int ubase = (qt < 16) ? qt : (qt < 32) ? 16 + (qt - 16) * 2 + ci
            : (qt < 48) ? 48 + (qt - 32) * 3 + ci : 96 + (qt - 48) * 4 + ci;
  const int punit = bh * 160 + ubase;

  const int b = bh >> 4, hd = bh & 15;
  const int q_base = qt * 32;

  const u16* Qb = qkv + ((size_t)(b * S_ + q_base + l31)) * 3072 + hd * 64;
  const u16* Kb = qkv + (size_t)b * S_ * 3072 + 1024 + hd * 64;
  const u16* Vt = vT + (size_t)bh * 64 * S_;

  short8 qf[4];
  #pragma unroll
  for (int dt = 0; dt < 4; dt++) {
    short8 v = *reinterpret_cast<const short8*>(Qb + dt * 16 + half * 8);
    #pragma unroll
    for (int jj = 0; jj < 8; jj++) v[jj] = (short)f2bf(bf2f((u16)v[jj]) * 0.125f);
    qf[dt] = v;
  }

  // cooperative staging: 1 GLDS K + 1 GLDS V per thread per tile
  auto stageKV = [&](int kt, int buf) {
    {
      int row = tid >> 3, cs = tid & 7;
      int c = cs ^ (row & 7);
      const u16* gp = Kb + (size_t)(kt * 32 + row) * 3072 + c * 8;
      GLDS(gp, (char*)&Kl[buf][0] + tid * 16);
    }
    {
      int row = tid >> 2, cs = tid & 3;
      int c = cs ^ (row & 3);
      const u16* gp = Vt + (size_t)row * S_ + kt * 32 + c * 8;
      GLDS(gp, (char*)&Vl[buf][0] + tid * 16);
    }
  };

  f32x16 o0, o1;
  #pragma unroll
  for (int r = 0; r < 16; r++) { o0[r] = 0.f; o1[r] = 0.f; }
  float m = -1e30f, lsum = 0.f;

  stageKV(kt0, 0);
  VMC(0); BAR();

  for (int i = 0; ; i++) {
    const int kt = kt0 + i;
    const int buf = i & 1;
    if (i < nt) stageKV(kt + 1, buf ^ 1);   // async, flies under compute

    if (kt <= qt) {
      const bool diag = (kt == qt);
      // K frags (swizzled ds_read)
      short8 kfr[4], vfr[4];
      #pragma unroll
      for (int dt = 0; dt < 4; dt++) {
        int cs = (dt * 2 + half) ^ (l31 & 7);
        kfr[dt] = *reinterpret_cast<const short8*>((const char*)&Kl[buf][0] + l31 * 128 + cs * 16);
      }
      {
        int r0 = l31, r1 = 32 + l31;
        vfr[0] = *reinterpret_cast<const short8*>((const char*)&Vl[buf][0] + r0 * 64 + ((half       ^ (r0 & 3)) * 16));
        vfr[1] = *reinterpret_cast<const short8*>((const char*)&Vl[buf][0] + r0 * 64 + (((2 + half) ^ (r0 & 3)) * 16));
        vfr[2] = *reinterpret_cast<const short8*>((const char*)&Vl[buf][0] + r1 * 64 + ((half       ^ (r1 & 3)) * 16));
        vfr[3] = *reinterpret_cast<const short8*>((const char*)&Vl[buf][0] + r1 * 64 + (((2 + half) ^ (r1 & 3)) * 16));
      }

      f32x16 s;
      #pragma unroll
      for (int r = 0; r < 16; r++) s[r] = 0.f;
      __builtin_amdgcn_s_setprio(1);
      #pragma unroll
      for (int dt = 0; dt < 4; dt++)
        s = __builtin_amdgcn_mfma_f32_32x32x16_bf16(kfr[dt], qf[dt], s, 0, 0, 0);
      __builtin_amdgcn_s_setprio(0);

      float p[16];
      #pragma unroll
      for (int r = 0; r < 16; r++) {
        p[r] = s[r];
        if (diag) {
          int kloc = half * 4 + (r & 3) + 8 * (r >> 2);
          if (kloc > l31) p[r] = -1e30f;
        }
      }
      float rm = p[0];
      #pragma unroll
      for (int r = 1; r < 16; r++) rm = fmaxf(rm, p[r]);
      rm = fmaxf(rm, __shfl_xor(rm, 32, 64));

      if (__any(rm > m + 8.0f)) {             // defer-max rescale (T13)
        float mn = fmaxf(m, rm);
        float alpha = __expf(m - mn);
        m = mn;
        lsum *= alpha;
        #pragma unroll
        for (int r = 0; r < 16; r++) {
          int row = (r & 3) + 8 * (r >> 2) + 4 * half;
          float ar = __shfl(alpha, row, 64);
          o0[r] *= ar; o1[r] *= ar;
        }
      }
      float rs = 0.f;
      #pragma unroll
      for (int r = 0; r < 16; r++) { p[r] = __expf(p[r] - m); rs += p[r]; }
      rs += __shfl_xor(rs, 32, 64);
      lsum += rs;

      u32 pk[8], sp[8];
      #pragma unroll
      for (int ii = 0; ii < 8; ii++) {
        pk[ii] = (u32)f2bf(p[2 * ii]) | ((u32)f2bf(p[2 * ii + 1]) << 16);
        sp[ii] = (u32)__shfl_xor((int)pk[ii], 32, 64);
      }
      u32x4 a0 = { half ? sp[2] : pk[0], half ? sp[3] : pk[1],
                   half ? pk[2] : sp[0], half ? pk[3] : sp[1] };
      u32x4 a1 = { half ? sp[6] : pk[4], half ? sp[7] : pk[5],
                   half ? pk[6] : sp[4], half ? pk[7] : sp[5] };
      short8 pa0 = *reinterpret_cast<short8*>(&a0);
      short8 pa1 = *reinterpret_cast<short8*>(&a1);

      __builtin_amdgcn_s_setprio(1);
      o0 = __builtin_amdgcn_mfma_f32_32x32x16_bf16(pa0, vfr[0], o0, 0, 0, 0);
      o0 = __builtin_amdgcn_mfma_f32_32x32x16_bf16(pa1, vfr[1], o0, 0, 0, 0);
      o1 = __builtin_amdgcn_mfma_f32_32x32x16_bf16(pa0, vfr[2], o1, 0, 0, 0);
      o1 = __builtin_amdgcn_mfma_f32_32x32x16_bf16(pa1, vfr[3], o1, 0, 0, 0);
      __builtin_amdgcn_s_setprio(0);
    }

    if (i == nt) break;
    VMC(0); BAR();                            // next tile staged & visible
  }

  #pragma unroll
  for (int r = 0; r < 16; r++) {
    int row = (r & 3) + 8 * (r >> 2) + 4 * half;
    pO[(size_t)punit * 2048 + row * 64 + l31]      = f2bf(o0[r]);
    pO[(size_t)punit * 2048 + row * 64 + 32 + l31] = f2bf(o1[r]);
  }
  if (half == 0) {
    pML[punit * 64 + l31]      = m;
    pML[punit * 64 + 32 + l31] = lsum;
  }
}

// ---------------- combine partials -> att (parallel: block per (bh,qt)) ----------------
__global__ __launch_bounds__(256) void attn_combine(
    const u16* __restrict__ pO, const float* __restrict__ pML,
    u16* __restrict__ att) {
  int gw = blockIdx.x;                 // 0..2047
  int bh = gw >> 6, qt = gw & 63;
  int b = bh >> 4, hd = bh & 15;
  int nc = (qt >> 4) + 1;
  int base = (qt < 16) ? qt : (qt < 32) ? 16 + (qt - 16) * 2
           : (qt < 48) ? 48 + (qt - 32) * 3 : 96 + (qt - 48) * 4;
  int p0 = bh * 160 + base;
  int q  = threadIdx.x >> 3;
  int d  = (threadIdx.x & 7) * 8;

  float m0 = pML[p0 * 64 + q];
  float l0 = pML[p0 * 64 + 32 + q];
  float m1 = nc > 1 ? pML[(p0 + 1) * 64 + q]      : -1e30f;
  float l1 = nc > 1 ? pML[(p0 + 1) * 64 + 32 + q] : 0.f;
  float m2 = nc > 2 ? pML[(p0 + 2) * 64 + q]      : -1e30f;
  float l2 = nc > 2 ? pML[(p0 + 2) * 64 + 32 + q] : 0.f;
  float m3 = nc > 3 ? pML[(p0 + 3) * 64 + q]      : -1e30f;
  float l3 = nc > 3 ? pML[(p0 + 3) * 64 + 32 + q] : 0.f;
  float M = fmaxf(fmaxf(m0, m1), fmaxf(m2, m3));
  float w0 = __expf(m0 - M), w1 = __expf(m1 - M);
  float w2 = __expf(m2 - M), w3 = __expf(m3 - M);
  float L = l0 * w0 + l1 * w1 + l2 * w2 + l3 * w3;
  float invL = 1.0f / L;

  float o[8];
  short8 v0 = *reinterpret_cast<const short8*>(&pO[(size_t)p0 * 2048 + q * 64 + d]);
  #pragma unroll
  for (int jj = 0; jj < 8; jj++) o[jj] = bf2f((u16)v0[jj]) * w0;
  if (nc > 1) {
    short8 v = *reinterpret_cast<const short8*>(&pO[(size_t)(p0 + 1) * 2048 + q * 64 + d]);
    #pragma unroll
    for (int jj = 0; jj < 8; jj++) o[jj] += bf2f((u16)v[jj]) * w1;
  }
  if (nc > 2) {
    short8 v = *reinterpret_cast<const short8*>(&pO[(size_t)(p0 + 2) * 2048 + q * 64 + d]);
    #pragma unroll
    for (int jj = 0; jj < 8; jj++) o[jj] += bf2f((u16)v[jj]) * w2;
  }
  if (nc > 3) {
    short8 v = *reinterpret_cast<const short8*>(&pO[(size_t)(p0 + 3) * 2048 + q * 64 + d]);
    #pragma unroll
    for (int jj = 0; jj < 8; jj++) o[jj] += bf2f((u16)v[jj]) * w3;
  }
  short8 ov;
  #pragma unroll
  for (int jj = 0; jj < 8; jj++) ov[jj] = (short)f2bf(o[jj] * invL);
  *reinterpret_cast<short8*>(
      &att[((size_t)(b * S_ + qt * 32 + q)) * D_ + hd * 64 + d]) = ov;
}

// ---------------- host launch ----------------
extern "C" void kernel_launch(void* const* d_in, const int* in_sizes, int n_in,
                              void* d_out, int out_size, void* d_ws, size_t ws_size,
                              hipStream_t stream) {
  (void)in_sizes; (void)n_in; (void)out_size; (void)ws_size;
  const float* x    = (const float*)d_in[0];
  const float* Wq   = (const float*)d_in[1];
  const float* Wk   = (const float*)d_in[2];
  const float* Wv   = (const float*)d_in[3];
  const float* Wo   = (const float*)d_in[4];
  const float* Wff  = (const float*)d_in[5];
  const float* Wout = (const float*)d_in[6];
  float* out = (float*)d_out;

  char* ws = (char*)d_ws;
  u16*   wqkv = (u16*)(ws);                    // [3072,1024] bf16, 6MB
  u16*   wo   = (u16*)(ws + 6291456);          // [1024,1024], 2MB
  u16*   wff  = (u16*)(ws + 8388608);          // [8192,1024], 16MB
  u16*   wout = (u16*)(ws + 25165824);         // [1024,4096], 8MB
  float* x1   = (float*)(ws + 33554432);       // [4096,1024] f32, 16MB
  char*  P    = ws + 50331648;                 // reuse pool
  u16*   hbuf = (u16*)(P);                     // [4096,1024], 8MB
  u16*   qkv  = (u16*)(P + 8388608);           // [4096,3072], 24MB
  u16*   vT   = (u16*)(P + 33554432);          // [32,64,2048], 8MB
  u16*   att  = (u16*)(P + 41943040);          // [4096,1024], 8MB
  u16*   pO   = (u16*)(P + 50331648);          // [5120,2048] bf16, 21MB (attn phase only)
  float* pML  = (float*)(P + 71303168);        // [5120,64] f32, 1.3MB
  u16*   h2   = (u16*)(P);                     // reuse hbuf slot
  u16*   s1   = (u16*)(P + 8388608);           // [4096,4096], 32MB
  u16*   gbuf = (u16*)(P + 41943040);          // [4096,4096], 32MB

  conv_f32_bf16<<<1024, 256, 0, stream>>>(Wq, wqkv,               262144);
  conv_f32_bf16<<<1024, 256, 0, stream>>>(Wk, wqkv + 1048576,     262144);
  conv_f32_bf16<<<1024, 256, 0, stream>>>(Wv, wqkv + 2097152,     262144);
  conv_f32_bf16<<<1024, 256, 0, stream>>>(Wo, wo,                 262144);
  conv_f32_bf16<<<8192, 256, 0, stream>>>(Wff, wff,               2097152);
  conv_f32_bf16<<<4096, 256, 0, stream>>>(Wout, wout,             1048576);

  ln_rows<<<M_, 256, 0, stream>>>(x, hbuf);
  gemm256<0><<<dim3(12, 16), 512, 0, stream>>>(hbuf, wqkv, qkv, nullptr, M_, 3072, 1024);
  transpose_v<<<dim3(32, 32), 256, 0, stream>>>(qkv, vT);
  attn_split<<<dim3(1280), 256, 0, stream>>>(qkv, vT, pO, pML);
  attn_combine<<<dim3(2048), 256, 0, stream>>>(pO, pML, att);
  gemm_bt<1><<<dim3(8, 32), 256, 0, stream>>>(att, wo, x1, nullptr, x, M_, 1024, 1024);

  ln_rows<<<M_, 256, 0, stream>>>(x1, h2);
  gemm256<2><<<dim3(16, 16), 512, 0, stream>>>(h2, wff, s1, nullptr, M_, 4096, 1024);
  gemm256<3><<<dim3(16, 16), 512, 0, stream>>>(h2, wff + 4194304, gbuf, s1, M_, 4096, 1024);
  gemm_bt<1><<<dim3(8, 32), 256, 0, stream>>>(gbuf, wout, out, nullptr, x1, M_, 1024, 4096);
}

// Round 6
// 276.700 us; speedup vs baseline: 1.4180x; 1.1768x over previous
//
#include <hip/hip_runtime.h>
#include <hip/hip_bf16.h>

#define B_ 2
#define S_ 2048
#define D_ 1024
#define H_ 16
#define FF_ 4096
#define M_ (B_*S_)   // 4096

using u16 = unsigned short;
using u32 = unsigned int;
typedef __attribute__((ext_vector_type(8))) short short8;
typedef __attribute__((ext_vector_type(4))) float f32x4;
typedef __attribute__((ext_vector_type(16))) float f32x16;
typedef __attribute__((ext_vector_type(4))) unsigned short u16x4;
typedef __attribute__((ext_vector_type(4))) unsigned int u32x4;

static __device__ __forceinline__ u16 f2bf(float f) {
  __hip_bfloat16 h = __float2bfloat16(f);
  return *reinterpret_cast<u16*>(&h);
}
static __device__ __forceinline__ float bf2f(u16 u) {
  __hip_bfloat16 h; *reinterpret_cast<u16*>(&h) = u;
  return __bfloat162float(h);
}

#define GLDS(gp, lp) __builtin_amdgcn_global_load_lds( \
    (const __attribute__((address_space(1))) void*)(gp), \
    (__attribute__((address_space(3))) void*)(lp), 16, 0, 0)

#define MFMA16(a, b, c) __builtin_amdgcn_mfma_f32_16x16x32_bf16(a, b, c, 0, 0, 0)
#define BAR() __builtin_amdgcn_s_barrier()
#define LGKM0() asm volatile("s_waitcnt lgkmcnt(0)" ::: "memory")
#define VMC(n) asm volatile("s_waitcnt vmcnt(" #n ")" ::: "memory")

// ---------------- fp32 -> bf16 conversion ----------------
__global__ __launch_bounds__(256) void conv_f32_bf16(
    const float* __restrict__ src, u16* __restrict__ dst, int n4) {
  int i = blockIdx.x * 256 + threadIdx.x;
  if (i < n4) {
    float4 v = reinterpret_cast<const float4*>(src)[i];
    u16x4 o;
    o.x = f2bf(v.x); o.y = f2bf(v.y); o.z = f2bf(v.z); o.w = f2bf(v.w);
    reinterpret_cast<u16x4*>(dst)[i] = o;
  }
}

// ---------------- LayerNorm (non-parametric), fp32 in -> bf16 out ----------------
__global__ __launch_bounds__(256) void ln_rows(
    const float* __restrict__ x, u16* __restrict__ out) {
  int row = blockIdx.x;
  int t = threadIdx.x;
  float4 v = reinterpret_cast<const float4*>(x + (size_t)row * D_)[t];
  float s  = v.x + v.y + v.z + v.w;
  float ss = v.x*v.x + v.y*v.y + v.z*v.z + v.w*v.w;
  #pragma unroll
  for (int off = 1; off < 64; off <<= 1) {
    s  += __shfl_xor(s,  off, 64);
    ss += __shfl_xor(ss, off, 64);
  }
  __shared__ float rs[4], rss[4];
  int wid = t >> 6;
  if ((t & 63) == 0) { rs[wid] = s; rss[wid] = ss; }
  __syncthreads();
  s  = rs[0] + rs[1] + rs[2] + rs[3];
  ss = rss[0] + rss[1] + rss[2] + rss[3];
  float mean = s * (1.0f / D_);
  float var  = ss * (1.0f / D_) - mean * mean;
  float r = rsqrtf(var + 1e-5f);
  u16x4 o;
  o.x = f2bf((v.x - mean) * r);
  o.y = f2bf((v.y - mean) * r);
  o.z = f2bf((v.z - mean) * r);
  o.w = f2bf((v.w - mean) * r);
  reinterpret_cast<u16x4*>(out + (size_t)row * D_)[t] = o;
}

// ---------------- 128x128 BT GEMM v2: prefetch-pipelined + swizzled ----------------
// C[M,N] = A[M,K] * W[N,K]^T. MODE 1: store fp32 = acc + res[M,N].
// T3-minimum 2-phase: stage(t+1) issued before compute(t), one barrier/iter.
// T2 XOR swizzle (chunk ^ row&7) on GLDS source and ds_read (rule #21).
template<int MODE>
__global__ __launch_bounds__(256, 2) void gemm_bt2(
    const u16* __restrict__ A, const u16* __restrict__ W,
    void* __restrict__ C, const u16* __restrict__ aux,
    const float* __restrict__ res, int M, int N, int K)
{
  __shared__ u16 lds[32768];  // A: 2 bufs x 8192, B at +16384: 2 bufs x 8192
  const int tid = threadIdx.x;
  const int wid = tid >> 6, lane = tid & 63;
  const int g = lane >> 4, c = lane & 15;
  const int gridN = N >> 7;
  int nwg = gridDim.x;
  int lin = blockIdx.x;
  lin = (lin & 7) * (nwg >> 3) + (lin >> 3);   // bijective XCD swizzle (nwg%8==0)
  const int bm = lin / gridN, bn = lin % gridN;
  const int wm = wid >> 1, wn = wid & 1;
  const int NT = K >> 6;

  f32x4 acc[4][4];
  #pragma unroll
  for (int i = 0; i < 4; i++)
    #pragma unroll
    for (int j = 0; j < 4; j++) acc[i][j] = {0.f, 0.f, 0.f, 0.f};

  auto stage = [&](int sel, int t) {
    const u16* src = sel ? W : A;
    const int tilerow = (sel ? bn : bm) * 128;
    char* dst = (char*)&lds[sel * 16384 + (t & 1) * 8192];
    #pragma unroll
    for (int i = 0; i < 4; i++) {
      int j = i * 256 + tid;
      int row = j >> 3, col16 = j & 7;
      const u16* gp = src + (size_t)(tilerow + row) * K + t * 64 + ((col16 ^ (row & 7)) << 3);
      GLDS(gp, dst + j * 16);
    }
  };

  stage(0, 0); stage(1, 0);
  __syncthreads();

  for (int t = 0; t < NT; t++) {
    const int buf = t & 1;
    if (t + 1 < NT) { stage(0, t + 1); stage(1, t + 1); }  // flies under compute

    short8 af[2][4], bfr[2][4];
    #pragma unroll
    for (int ks = 0; ks < 2; ks++)
      #pragma unroll
      for (int m = 0; m < 4; m++) {
        int rh = wm * 64 + m * 16 + c;
        af[ks][m] = *reinterpret_cast<const short8*>(
            &lds[buf * 8192 + rh * 64 + ((((ks << 2) | g) ^ (rh & 7)) << 3)]);
      }
    #pragma unroll
    for (int ks = 0; ks < 2; ks++)
      #pragma unroll
      for (int n = 0; n < 4; n++) {
        int rh = wn * 64 + n * 16 + c;
        bfr[ks][n] = *reinterpret_cast<const short8*>(
            &lds[16384 + buf * 8192 + rh * 64 + ((((ks << 2) | g) ^ (rh & 7)) << 3)]);
      }
    __builtin_amdgcn_s_setprio(1);
    #pragma unroll
    for (int m = 0; m < 4; m++)
      #pragma unroll
      for (int n = 0; n < 4; n++) {
        acc[m][n] = MFMA16(af[0][m], bfr[0][n], acc[m][n]);
        acc[m][n] = MFMA16(af[1][m], bfr[1][n], acc[m][n]);
      }
    __builtin_amdgcn_s_setprio(0);
    __syncthreads();   // implicit vmcnt(0): t+1 staged & visible
  }

  #pragma unroll
  for (int m = 0; m < 4; m++)
    #pragma unroll
    for (int n = 0; n < 4; n++)
      #pragma unroll
      for (int r = 0; r < 4; r++) {
        int gr = bm * 128 + wm * 64 + m * 16 + g * 4 + r;
        int gc = bn * 128 + wn * 64 + n * 16 + c;
        size_t idx = (size_t)gr * N + gc;
        float v = acc[m][n][r];
        if (MODE == 0) {
          ((u16*)C)[idx] = f2bf(v);
        } else if (MODE == 1) {
          ((float*)C)[idx] = v + res[idx];
        } else if (MODE == 2) {
          ((u16*)C)[idx] = f2bf(v / (1.0f + __expf(-v)));
        } else {
          ((u16*)C)[idx] = f2bf(v * bf2f(aux[idx]));
        }
      }
}

// ---------------- 256x256 8-phase BT GEMM (T2+T3+T4+T5) ----------------
template<int MODE>
__global__ __launch_bounds__(512, 2) void gemm256(
    const u16* __restrict__ A, const u16* __restrict__ W,
    void* __restrict__ C, const u16* __restrict__ aux, int M, int N, int K)
{
  __shared__ u16 lds[65536];
  const int tid = threadIdx.x;
  const int wid = tid >> 6, lane = tid & 63;
  const int g = lane >> 4, c = lane & 15;
  const int wm = wid >> 2, wn = wid & 3;

  const int gridN = N >> 8;
  int nwg = gridDim.x * gridDim.y;
  int lin = blockIdx.y * gridDim.x + blockIdx.x;
  lin = (lin & 7) * (nwg >> 3) + (lin >> 3);
  const int bm = lin / gridN, bn = lin % gridN;
  const int NT = K >> 6;

  f32x4 acc[8][4];
  #pragma unroll
  for (int i = 0; i < 8; i++)
    #pragma unroll
    for (int j = 0; j < 4; j++) acc[i][j] = {0.f, 0.f, 0.f, 0.f};

  auto stage = [&](int sel, int t, int half) {
    const u16* src = sel ? W : A;
    const int tilerow = (sel ? bn : bm) * 256 + half * 128;
    const int ldsb = sel * 32768 + (t & 1) * 16384 + half * 8192;
    #pragma unroll
    for (int i = 0; i < 2; i++) {
      int j = i * 512 + tid;
      int row = j >> 3, col16 = j & 7;
      const u16* gp = src + (size_t)(tilerow + row) * K + t * 64 + ((col16 ^ (row & 7)) << 3);
      GLDS(gp, (char*)lds + ldsb * 2 + j * 16);
    }
  };
  auto ldA = [&](short8 (&a)[2][4], int buf, int mh) {
    #pragma unroll
    for (int ks = 0; ks < 2; ks++)
      #pragma unroll
      for (int m = 0; m < 4; m++) {
        int rh = wm * 16 + m * 32 + c;
        a[ks][m] = *reinterpret_cast<const short8*>(
            &lds[buf * 16384 + mh * 8192 + rh * 64 + ((((ks << 2) | g) ^ (rh & 7)) << 3)]);
      }
  };
  auto ldB = [&](short8 (&b)[2][2], int buf, int nh) {
    #pragma unroll
    for (int ks = 0; ks < 2; ks++)
      #pragma unroll
      for (int n = 0; n < 2; n++) {
        int rh = wn * 16 + n * 64 + c;
        b[ks][n] = *reinterpret_cast<const short8*>(
            &lds[32768 + buf * 16384 + nh * 8192 + rh * 64 + ((((ks << 2) | g) ^ (rh & 7)) << 3)]);
      }
  };

#define MFMA_Q(a, b, mb, nb)                                            \
  __builtin_amdgcn_s_setprio(1);                                        \
  _Pragma("unroll")                                                     \
  for (int m = 0; m < 4; m++)                                           \
    _Pragma("unroll")                                                   \
    for (int n = 0; n < 2; n++) {                                       \
      acc[(mb)+m][(nb)+n] = MFMA16(a[0][m], b[0][n], acc[(mb)+m][(nb)+n]); \
      acc[(mb)+m][(nb)+n] = MFMA16(a[1][m], b[1][n], acc[(mb)+m][(nb)+n]); \
    }                                                                   \
  __builtin_amdgcn_s_setprio(0);

  stage(0, 0, 0); stage(1, 0, 0); stage(0, 0, 1); stage(1, 0, 1);
  stage(0, 1, 0); stage(1, 1, 0);
  VMC(4);
  BAR();

  for (int t = 0; t < NT; t += 2) {
    const int buf = t & 1;
    short8 a0[2][4], a1[2][4], b0[2][2], b1[2][2];
    ldA(a0, buf, 0); ldB(b0, buf, 0);
    stage(0, t + 1, 1);
    BAR(); LGKM0();
    MFMA_Q(a0, b0, 0, 0);
    BAR();
    ldB(b1, buf, 1);
    stage(1, t + 1, 1);
    BAR(); LGKM0();
    MFMA_Q(a0, b1, 0, 2);
    BAR();
    ldA(a1, buf, 1);
    if (t + 2 < NT) stage(0, t + 2, 0);
    BAR(); LGKM0();
    MFMA_Q(a1, b0, 4, 0);
    BAR();
    if (t + 2 < NT) { stage(1, t + 2, 0); VMC(4); } else { VMC(0); }
    BAR(); LGKM0();
    MFMA_Q(a1, b1, 4, 2);
    BAR();
    ldA(a0, buf ^ 1, 0); ldB(b0, buf ^ 1, 0);
    if (t + 2 < NT) stage(0, t + 2, 1);
    BAR(); LGKM0();
    MFMA_Q(a0, b0, 0, 0);
    BAR();
    ldB(b1, buf ^ 1, 1);
    if (t + 2 < NT) stage(1, t + 2, 1);
    BAR(); LGKM0();
    MFMA_Q(a0, b1, 0, 2);
    BAR();
    ldA(a1, buf ^ 1, 1);
    if (t + 3 < NT) stage(0, t + 3, 0);
    BAR(); LGKM0();
    MFMA_Q(a1, b0, 4, 0);
    BAR();
    if (t + 3 < NT) { stage(1, t + 3, 0); VMC(4); } else { VMC(0); }
    BAR(); LGKM0();
    MFMA_Q(a1, b1, 4, 2);
    BAR();
  }

  #pragma unroll
  for (int m = 0; m < 8; m++)
    #pragma unroll
    for (int n = 0; n < 4; n++)
      #pragma unroll
      for (int r = 0; r < 4; r++) {
        int gr = bm * 256 + (m >> 2) * 128 + wm * 16 + (m & 3) * 32 + g * 4 + r;
        int gc = bn * 256 + (n >> 1) * 128 + wn * 16 + (n & 1) * 64 + c;
        size_t idx = (size_t)gr * N + gc;
        float v = acc[m][n][r];
        if (MODE == 0) {
          ((u16*)C)[idx] = f2bf(v);
        } else if (MODE == 2) {
          ((u16*)C)[idx] = f2bf(v / (1.0f + __expf(-v)));
        } else {
          ((u16*)C)[idx] = f2bf(v * bf2f(aux[idx]));
        }
      }
#undef MFMA_Q
}

// ---------------- V transpose: qkv v-section -> vT [B*H, 64, S] ----------------
__global__ __launch_bounds__(256) void transpose_v(
    const u16* __restrict__ qkv, u16* __restrict__ vT) {
  __shared__ u16 t[64][66];
  int bh = blockIdx.y;
  int s0 = blockIdx.x * 64;
  int b = bh >> 4, h = bh & 15;
  int tid = threadIdx.x;
  #pragma unroll
  for (int it = 0; it < 2; it++) {
    int idx = it * 256 + tid;
    int row = idx >> 3;
    int cc  = (idx & 7) * 8;
    const u16* src = qkv + ((size_t)(b * S_ + s0 + row)) * 3072 + 2048 + h * 64 + cc;
    short8 v = *reinterpret_cast<const short8*>(src);
    #pragma unroll
    for (int j = 0; j < 8; j++) t[row][cc + j] = (u16)v[j];
  }
  __syncthreads();
  #pragma unroll
  for (int it = 0; it < 2; it++) {
    int idx = it * 256 + tid;
    int d  = idx >> 3;
    int sc = (idx & 7) * 8;
    short8 o;
    #pragma unroll
    for (int j = 0; j < 8; j++) o[j] = (short)t[sc + j][d];
    *reinterpret_cast<short8*>(vT + ((size_t)bh * 64 + d) * S_ + s0 + sc) = o;
  }
}

// ---------------- split-KV causal flash attention, block-cooperative LDS K/V ----------------
__global__ __launch_bounds__(256) void attn_split(
    const u16* __restrict__ qkv, const u16* __restrict__ vT,
    u16* __restrict__ pO, float* __restrict__ pML) {
  __shared__ u16 Kl[2][2048];   // [buf][32 rows x 64 d]
  __shared__ u16 Vl[2][2048];   // [buf][64 rows(d) x 32 s]
  const int tid  = threadIdx.x;
  const int lane = tid & 63;
  const int wid  = tid >> 6;
  const int l31  = lane & 31;
  const int half = lane >> 5;

  int lin = blockIdx.x;                       // 0..1279
  int swz = (lin & 7) * 160 + (lin >> 3);     // XCD swizzle: 4 heads/XCD
  int bh  = swz / 40;
  int j   = swz - bh * 40;
  int qq = 15, rem = j;                       // heavy quads first
  while (rem > (qq >> 2)) { rem -= (qq >> 2) + 1; qq--; }
  int ci = rem;
  const int qt  = qq * 4 + wid;
  const int kt0 = ci * 16;
  const int nt  = min(qq * 4 + 3, kt0 + 15) - kt0;  // block-uniform iter count-1
  int ubase = (qt < 16) ? qt : (qt < 32) ? 16 + (qt - 16) * 2 + ci
            : (qt < 48) ? 48 + (qt - 32) * 3 + ci : 96 + (qt - 48) * 4 + ci;
  const int punit = bh * 160 + ubase;

  const int b = bh >> 4, hd = bh & 15;
  const int q_base = qt * 32;

  const u16* Qb = qkv + ((size_t)(b * S_ + q_base + l31)) * 3072 + hd * 64;
  const u16* Kb = qkv + (size_t)b * S_ * 3072 + 1024 + hd * 64;
  const u16* Vt = vT + (size_t)bh * 64 * S_;

  short8 qf[4];
  #pragma unroll
  for (int dt = 0; dt < 4; dt++) {
    short8 v = *reinterpret_cast<const short8*>(Qb + dt * 16 + half * 8);
    #pragma unroll
    for (int jj = 0; jj < 8; jj++) v[jj] = (short)f2bf(bf2f((u16)v[jj]) * 0.125f);
    qf[dt] = v;
  }

  auto stageKV = [&](int kt, int buf) {
    {
      int row = tid >> 3, cs = tid & 7;
      int c = cs ^ (row & 7);
      const u16* gp = Kb + (size_t)(kt * 32 + row) * 3072 + c * 8;
      GLDS(gp, (char*)&Kl[buf][0] + tid * 16);
    }
    {
      int row = tid >> 2, cs = tid & 3;
      int c = cs ^ (row & 3);
      const u16* gp = Vt + (size_t)row * S_ + kt * 32 + c * 8;
      GLDS(gp, (char*)&Vl[buf][0] + tid * 16);
    }
  };

  f32x16 o0, o1;
  #pragma unroll
  for (int r = 0; r < 16; r++) { o0[r] = 0.f; o1[r] = 0.f; }
  float m = -1e30f, lsum = 0.f;

  stageKV(kt0, 0);
  VMC(0); BAR();

  for (int i = 0; ; i++) {
    const int kt = kt0 + i;
    const int buf = i & 1;
    if (i < nt) stageKV(kt + 1, buf ^ 1);   // async, flies under compute

    if (kt <= qt) {
      const bool diag = (kt == qt);
      short8 kfr[4], vfr[4];
      #pragma unroll
      for (int dt = 0; dt < 4; dt++) {
        int cs = (dt * 2 + half) ^ (l31 & 7);
        kfr[dt] = *reinterpret_cast<const short8*>((const char*)&Kl[buf][0] + l31 * 128 + cs * 16);
      }
      {
        int r0 = l31, r1 = 32 + l31;
        vfr[0] = *reinterpret_cast<const short8*>((const char*)&Vl[buf][0] + r0 * 64 + ((half       ^ (r0 & 3)) * 16));
        vfr[1] = *reinterpret_cast<const short8*>((const char*)&Vl[buf][0] + r0 * 64 + (((2 + half) ^ (r0 & 3)) * 16));
        vfr[2] = *reinterpret_cast<const short8*>((const char*)&Vl[buf][0] + r1 * 64 + ((half       ^ (r1 & 3)) * 16));
        vfr[3] = *reinterpret_cast<const short8*>((const char*)&Vl[buf][0] + r1 * 64 + (((2 + half) ^ (r1 & 3)) * 16));
      }

      f32x16 s;
      #pragma unroll
      for (int r = 0; r < 16; r++) s[r] = 0.f;
      __builtin_amdgcn_s_setprio(1);
      #pragma unroll
      for (int dt = 0; dt < 4; dt++)
        s = __builtin_amdgcn_mfma_f32_32x32x16_bf16(kfr[dt], qf[dt], s, 0, 0, 0);
      __builtin_amdgcn_s_setprio(0);

      float p[16];
      #pragma unroll
      for (int r = 0; r < 16; r++) {
        p[r] = s[r];
        if (diag) {
          int kloc = half * 4 + (r & 3) + 8 * (r >> 2);
          if (kloc > l31) p[r] = -1e30f;
        }
      }
      float rm = p[0];
      #pragma unroll
      for (int r = 1; r < 16; r++) rm = fmaxf(rm, p[r]);
      rm = fmaxf(rm, __shfl_xor(rm, 32, 64));

      if (__any(rm > m + 8.0f)) {             // defer-max rescale (T13)
        float mn = fmaxf(m, rm);
        float alpha = __expf(m - mn);
        m = mn;
        lsum *= alpha;
        #pragma unroll
        for (int r = 0; r < 16; r++) {
          int row = (r & 3) + 8 * (r >> 2) + 4 * half;
          float ar = __shfl(alpha, row, 64);
          o0[r] *= ar; o1[r] *= ar;
        }
      }
      float rs = 0.f;
      #pragma unroll
      for (int r = 0; r < 16; r++) { p[r] = __expf(p[r] - m); rs += p[r]; }
      rs += __shfl_xor(rs, 32, 64);
      lsum += rs;

      u32 pk[8], sp[8];
      #pragma unroll
      for (int ii = 0; ii < 8; ii++) {
        pk[ii] = (u32)f2bf(p[2 * ii]) | ((u32)f2bf(p[2 * ii + 1]) << 16);
        sp[ii] = (u32)__shfl_xor((int)pk[ii], 32, 64);
      }
      u32x4 a0 = { half ? sp[2] : pk[0], half ? sp[3] : pk[1],
                   half ? pk[2] : sp[0], half ? pk[3] : sp[1] };
      u32x4 a1 = { half ? sp[6] : pk[4], half ? sp[7] : pk[5],
                   half ? pk[6] : sp[4], half ? pk[7] : sp[5] };
      short8 pa0 = *reinterpret_cast<short8*>(&a0);
      short8 pa1 = *reinterpret_cast<short8*>(&a1);

      __builtin_amdgcn_s_setprio(1);
      o0 = __builtin_amdgcn_mfma_f32_32x32x16_bf16(pa0, vfr[0], o0, 0, 0, 0);
      o0 = __builtin_amdgcn_mfma_f32_32x32x16_bf16(pa1, vfr[1], o0, 0, 0, 0);
      o1 = __builtin_amdgcn_mfma_f32_32x32x16_bf16(pa0, vfr[2], o1, 0, 0, 0);
      o1 = __builtin_amdgcn_mfma_f32_32x32x16_bf16(pa1, vfr[3], o1, 0, 0, 0);
      __builtin_amdgcn_s_setprio(0);
    }

    if (i == nt) break;
    VMC(0); BAR();                            // next tile staged & visible
  }

  #pragma unroll
  for (int r = 0; r < 16; r++) {
    int row = (r & 3) + 8 * (r >> 2) + 4 * half;
    pO[(size_t)punit * 2048 + row * 64 + l31]      = f2bf(o0[r]);
    pO[(size_t)punit * 2048 + row * 64 + 32 + l31] = f2bf(o1[r]);
  }
  if (half == 0) {
    pML[punit * 64 + l31]      = m;
    pML[punit * 64 + 32 + l31] = lsum;
  }
}

// ---------------- combine partials -> att (parallel: block per (bh,qt)) ----------------
__global__ __launch_bounds__(256) void attn_combine(
    const u16* __restrict__ pO, const float* __restrict__ pML,
    u16* __restrict__ att) {
  int gw = blockIdx.x;                 // 0..2047
  int bh = gw >> 6, qt = gw & 63;
  int b = bh >> 4, hd = bh & 15;
  int nc = (qt >> 4) + 1;
  int base = (qt < 16) ? qt : (qt < 32) ? 16 + (qt - 16) * 2
           : (qt < 48) ? 48 + (qt - 32) * 3 : 96 + (qt - 48) * 4;
  int p0 = bh * 160 + base;
  int q  = threadIdx.x >> 3;
  int d  = (threadIdx.x & 7) * 8;

  float m0 = pML[p0 * 64 + q];
  float l0 = pML[p0 * 64 + 32 + q];
  float m1 = nc > 1 ? pML[(p0 + 1) * 64 + q]      : -1e30f;
  float l1 = nc > 1 ? pML[(p0 + 1) * 64 + 32 + q] : 0.f;
  float m2 = nc > 2 ? pML[(p0 + 2) * 64 + q]      : -1e30f;
  float l2 = nc > 2 ? pML[(p0 + 2) * 64 + 32 + q] : 0.f;
  float m3 = nc > 3 ? pML[(p0 + 3) * 64 + q]      : -1e30f;
  float l3 = nc > 3 ? pML[(p0 + 3) * 64 + 32 + q] : 0.f;
  float M = fmaxf(fmaxf(m0, m1), fmaxf(m2, m3));
  float w0 = __expf(m0 - M), w1 = __expf(m1 - M);
  float w2 = __expf(m2 - M), w3 = __expf(m3 - M);
  float L = l0 * w0 + l1 * w1 + l2 * w2 + l3 * w3;
  float invL = 1.0f / L;

  float o[8];
  short8 v0 = *reinterpret_cast<const short8*>(&pO[(size_t)p0 * 2048 + q * 64 + d]);
  #pragma unroll
  for (int jj = 0; jj < 8; jj++) o[jj] = bf2f((u16)v0[jj]) * w0;
  if (nc > 1) {
    short8 v = *reinterpret_cast<const short8*>(&pO[(size_t)(p0 + 1) * 2048 + q * 64 + d]);
    #pragma unroll
    for (int jj = 0; jj < 8; jj++) o[jj] += bf2f((u16)v[jj]) * w1;
  }
  if (nc > 2) {
    short8 v = *reinterpret_cast<const short8*>(&pO[(size_t)(p0 + 2) * 2048 + q * 64 + d]);
    #pragma unroll
    for (int jj = 0; jj < 8; jj++) o[jj] += bf2f((u16)v[jj]) * w2;
  }
  if (nc > 3) {
    short8 v = *reinterpret_cast<const short8*>(&pO[(size_t)(p0 + 3) * 2048 + q * 64 + d]);
    #pragma unroll
    for (int jj = 0; jj < 8; jj++) o[jj] += bf2f((u16)v[jj]) * w3;
  }
  short8 ov;
  #pragma unroll
  for (int jj = 0; jj < 8; jj++) ov[jj] = (short)f2bf(o[jj] * invL);
  *reinterpret_cast<short8*>(
      &att[((size_t)(b * S_ + qt * 32 + q)) * D_ + hd * 64 + d]) = ov;
}

// ---------------- host launch ----------------
extern "C" void kernel_launch(void* const* d_in, const int* in_sizes, int n_in,
                              void* d_out, int out_size, void* d_ws, size_t ws_size,
                              hipStream_t stream) {
  (void)in_sizes; (void)n_in; (void)out_size; (void)ws_size;
  const float* x    = (const float*)d_in[0];
  const float* Wq   = (const float*)d_in[1];
  const float* Wk   = (const float*)d_in[2];
  const float* Wv   = (const float*)d_in[3];
  const float* Wo   = (const float*)d_in[4];
  const float* Wff  = (const float*)d_in[5];
  const float* Wout = (const float*)d_in[6];
  float* out = (float*)d_out;

  char* ws = (char*)d_ws;
  u16*   wqkv = (u16*)(ws);                    // [3072,1024] bf16, 6MB
  u16*   wo   = (u16*)(ws + 6291456);          // [1024,1024], 2MB
  u16*   wff  = (u16*)(ws + 8388608);          // [8192,1024], 16MB
  u16*   wout = (u16*)(ws + 25165824);         // [1024,4096], 8MB
  float* x1   = (float*)(ws + 33554432);       // [4096,1024] f32, 16MB
  char*  P    = ws + 50331648;                 // reuse pool
  u16*   hbuf = (u16*)(P);                     // [4096,1024], 8MB
  u16*   qkv  = (u16*)(P + 8388608);           // [4096,3072], 24MB
  u16*   vT   = (u16*)(P + 33554432);          // [32,64,2048], 8MB
  u16*   att  = (u16*)(P + 41943040);          // [4096,1024], 8MB
  u16*   pO   = (u16*)(P + 50331648);          // [5120,2048] bf16, 21MB (attn phase only)
  float* pML  = (float*)(P + 71303168);        // [5120,64] f32, 1.3MB
  u16*   h2   = (u16*)(P);                     // reuse hbuf slot
  u16*   s1   = (u16*)(P + 8388608);           // [4096,4096], 32MB
  u16*   gbuf = (u16*)(P + 41943040);          // [4096,4096], 32MB

  conv_f32_bf16<<<1024, 256, 0, stream>>>(Wq, wqkv,               262144);
  conv_f32_bf16<<<1024, 256, 0, stream>>>(Wk, wqkv + 1048576,     262144);
  conv_f32_bf16<<<1024, 256, 0, stream>>>(Wv, wqkv + 2097152,     262144);
  conv_f32_bf16<<<1024, 256, 0, stream>>>(Wo, wo,                 262144);
  conv_f32_bf16<<<8192, 256, 0, stream>>>(Wff, wff,               2097152);
  conv_f32_bf16<<<4096, 256, 0, stream>>>(Wout, wout,             1048576);

  ln_rows<<<M_, 256, 0, stream>>>(x, hbuf);
  gemm256<0><<<dim3(12, 16), 512, 0, stream>>>(hbuf, wqkv, qkv, nullptr, M_, 3072, 1024);
  transpose_v<<<dim3(32, 32), 256, 0, stream>>>(qkv, vT);
  attn_split<<<dim3(1280), 256, 0, stream>>>(qkv, vT, pO, pML);
  attn_combine<<<dim3(2048), 256, 0, stream>>>(pO, pML, att);
  gemm_bt2<1><<<dim3(256), 256, 0, stream>>>(att, wo, x1, nullptr, x, M_, 1024, 1024);

  ln_rows<<<M_, 256, 0, stream>>>(x1, h2);
  gemm256<2><<<dim3(16, 16), 512, 0, stream>>>(h2, wff, s1, nullptr, M_, 4096, 1024);
  gemm256<3><<<dim3(16, 16), 512, 0, stream>>>(h2, wff + 4194304, gbuf, s1, M_, 4096, 1024);
  gemm_bt2<1><<<dim3(256), 256, 0, stream>>>(gbuf, wout, out, nullptr, x1, M_, 1024, 4096);
}